// Round 12
// baseline (27.730 us; speedup 1.0000x reference)
//
#include <hip/hip_runtime.h>

// Problem constants (match reference).
#define BB   64
#define NN   900
#define MM   300
#define NC1  92          // NUM_CLASSES + 1
#define MQ   75          // float4 groups per m-row (300/4)
#define KN   4           // n-rows per thread
#define NCH  (NN / KN)   // 225
#define PERB (NCH * MQ)  // 16875 threads per batch
#define CPB  66          // ceil(16875/256) chunks per batch
#define BD   256

typedef float f32x2 __attribute__((ext_vector_type(2)));

static __device__ __forceinline__ f32x2 min2(f32x2 a, f32x2 b) {
    return f32x2{ fminf(a.x, b.x), fminf(a.y, b.y) };
}
static __device__ __forceinline__ f32x2 max2(f32x2 a, f32x2 b) {
    return f32x2{ fmaxf(a.x, b.x), fmaxf(a.y, b.y) };
}

__global__ __launch_bounds__(BD) void cost_kernel(
    const float4* __restrict__ bbox_pred,   // [B*N] (cx,cy,w,h)
    const float*  __restrict__ labels_pred, // [B*N*92]
    const float4* __restrict__ bbox_gt,     // [B*M]
    const int4*   __restrict__ labels_gt,   // [B*M/4]
    float4*       __restrict__ out)         // [B*N*MQ]
{
    __shared__ int4 lg_lds[MQ];             // 1.2 KB: this batch's label row

    const int b   = blockIdx.x / CPB;
    const int chk = blockIdx.x % CPB;
    const int t   = threadIdx.x;

    // ---- Stage labels_gt[b,:] (one coalesced 1.2 KB load) ----
    if (t < MQ) lg_lds[t] = labels_gt[b * MQ + t];

    const int ii    = chk * BD + t;
    const bool valid = (ii < PERB);
    const int  i    = valid ? ii : 0;
    const int  mq   = i % MQ;
    const int  nb   = i / MQ;
    const int  bn0  = b * NN + nb * KN;

    // ---- Independent global loads issued before the barrier ----
    float4 g4[4];
#pragma unroll
    for (int j = 0; j < 4; ++j)
        g4[j] = bbox_gt[b * MM + mq * 4 + j];

    float4 p4[KN];
#pragma unroll
    for (int k = 0; k < KN; ++k)
        p4[k] = bbox_pred[bn0 + k];

    __syncthreads();

    // ---- Short-latency label read, then gathers ----
    int4 lg = lg_lds[mq];
    int lbl[4] = { lg.x, lg.y, lg.z, lg.w };
    float cls1[KN][4];                       // 1 - cls, folded
#pragma unroll
    for (int k = 0; k < KN; ++k) {
        const float* lp = labels_pred + (size_t)(bn0 + k) * NC1;
#pragma unroll
        for (int j = 0; j < 4; ++j)
            cls1[k][j] = 1.0f - lp[lbl[j]];
    }

    // ---- gt state (packed) ----
    f32x2 gc[4], gs[4], gu[4], gd1[4], gs1[4];
    float ga[4];
#pragma unroll
    for (int j = 0; j < 4; ++j) {
        float4 g = g4[j];
        gc[j]  = f32x2{ g.x, g.y };
        gs[j]  = f32x2{ g.z, g.w };
        gu[j]  = gc[j] - 0.5f * gs[j];
        gs1[j] = gs[j] + 1.0f;
        gd1[j] = gu[j] + gs1[j];
        ga[j]  = gs1[j].x * gs1[j].y;
    }

    // ---- Compute + store ----
#pragma unroll
    for (int k = 0; k < KN; ++k) {
        float4 p = p4[k];
        f32x2 pc  = f32x2{ p.x, p.y };
        f32x2 ps  = f32x2{ p.z, p.w };
        f32x2 pu  = pc - 0.5f * ps;
        f32x2 ps1 = ps + 1.0f;
        f32x2 pd1 = pu + ps1;
        float parea = ps1.x * ps1.y;

        float res[4];
#pragma unroll
        for (int j = 0; j < 4; ++j) {
            f32x2 iwr = min2(pd1, gd1[j]) - max2(pu, gu[j]);
            f32x2 iw  = max2(iwr, f32x2{ 0.0f, 0.0f });
            float inter = iw.x * iw.y;

            f32x2 bw = (ps1 + gs1[j]) - iwr;      // bound-from-sum identity
            float barea = bw.x * bw.y;

            float uni   = (parea + ga[j]) - inter;
            float denom = uni * barea;
            float num   = inter * barea + uni * uni;   // iou+bg with ONE rcp
            float frac  = num * __builtin_amdgcn_rcpf(denom);

            f32x2 d1 = pc - gc[j];
            f32x2 d2 = ps - gs[j];
            float bbox = (fabsf(d1.x) + fabsf(d1.y))
                       + (fabsf(d2.x) + fabsf(d2.y));

            res[j] = (bbox + cls1[k][j]) - frac;
        }

        if (valid)
            out[(size_t)(bn0 + k) * MQ + mq] =
                make_float4(res[0], res[1], res[2], res[3]);
    }
}

extern "C" void kernel_launch(void* const* d_in, const int* in_sizes, int n_in,
                              void* d_out, int out_size, void* d_ws, size_t ws_size,
                              hipStream_t stream) {
    const float4* bbox_pred   = (const float4*)d_in[0];
    const float*  labels_pred = (const float*) d_in[1];
    const float4* bbox_gt     = (const float4*)d_in[2];
    const int4*   labels_gt   = (const int4*)  d_in[3];
    float4*       out         = (float4*)d_out;

    const int grid = BB * CPB;                // 4224 blocks
    cost_kernel<<<grid, BD, 0, stream>>>(bbox_pred, labels_pred, bbox_gt,
                                         labels_gt, out);
}